// Round 14
// baseline (206.787 us; speedup 1.0000x reference)
//
#include <hip/hip_runtime.h>
#include <hip/hip_fp16.h>
#include <math.h>

#define NN 50000
#define NE 800000
#define F 64
#define NCLS 16

#define BKS 7              // log2(nodes per bucket)
#define BKN 128            // nodes per bucket
#define NBK 391            // ceil(50000/128)
#define CAP 2560           // sedge slots per bucket region (avg 2048, +11 sigma)
#define B1C 4096           // edges per k_local block (dense chunk)
#define B1B 196            // ceil(NE/B1C)

typedef unsigned short u16;
typedef unsigned int u32;

// ---------------- pass 1: per-block LDS sort by bucket, DENSE writeback ----------

__global__ __launch_bounds__(512) void k_local(const int* __restrict__ row,
                                               const int* __restrict__ col,
                                               const float* __restrict__ w,
                                               int2* __restrict__ tmp,
                                               int* __restrict__ ghL,
                                               int* __restrict__ ghH) {
    __shared__ int hist[512], sa[512], sb[512], lcur[512];
    __shared__ int2 stage[B1C];
    int t = threadIdx.x;
    int e0 = blockIdx.x * B1C;
    int cnt = min(B1C, NE - e0);
    hist[t] = 0;
    __syncthreads();

    int mykey[8]; int myb[8]; int myw[8]; bool myv[8];
#pragma unroll
    for (int k = 0; k < 8; ++k) {
        int i = t + k * 512;
        myv[k] = (i < cnt);
        if (myv[k]) {
            int e = e0 + i;
            int c = col[e];
            myb[k]   = c >> BKS;
            mykey[k] = (row[e] << BKS) | (c & (BKN - 1));
            myw[k]   = __float_as_int(w[e]);
            atomicAdd(&hist[myb[k]], 1);
        }
    }
    __syncthreads();

    sa[t] = hist[t];
    __syncthreads();
    int* src = sa; int* dst = sb;
#pragma unroll
    for (int off = 1; off < 512; off <<= 1) {
        dst[t] = src[t] + ((t >= off) ? src[t - off] : 0);
        __syncthreads();
        int* tq = src; src = dst; dst = tq;
    }
    int lex = src[t] - hist[t];
    lcur[t] = lex;
    ghL[blockIdx.x * 512 + t] = lex;       // run start within this block's chunk
    ghH[blockIdx.x * 512 + t] = hist[t];   // run length
    __syncthreads();

#pragma unroll
    for (int k = 0; k < 8; ++k) {
        if (myv[k]) {
            int pos = atomicAdd(&lcur[myb[k]], 1);
            stage[pos] = make_int2(mykey[k], myw[k]);
        }
    }
    __syncthreads();

    for (int i = t; i < cnt; i += 512) tmp[e0 + i] = stage[i];
}

// ---------------- pass 2: one block per bucket: gather runs, node sort, dense out --
// Final sedge record = 4 bytes: (f16(w) << 16) | src.  dinv from exact f32 dsum.

__global__ __launch_bounds__(256) void k_bucket2(const int2* __restrict__ tmp,
                                                 const int* __restrict__ ghL,
                                                 const int* __restrict__ ghH,
                                                 u32* __restrict__ sedge,
                                                 int2* __restrict__ benode,
                                                 float* __restrict__ dinv) {
    __shared__ int2 stage[CAP];      // 20 KB
    __shared__ u32 sortedU[CAP];     // 10 KB
    __shared__ int lb[200], ps[200];
    __shared__ int ssa[256], ssb[256];
    __shared__ int hist[BKN], na[BKN], nb[BKN], lcur[BKN];
    __shared__ float dsum[BKN];
    int b = blockIdx.x;
    int t = threadIdx.x;
    int lnv = 0;
    if (t < B1B) {
        lb[t] = ghL[t * 512 + b];
        lnv   = ghH[t * 512 + b];
    }
    if (t < BKN) { hist[t] = 0; dsum[t] = 0.f; }
    ssa[t] = lnv;
    __syncthreads();
    int* src = ssa; int* dst = ssb;
#pragma unroll
    for (int off = 1; off < 256; off <<= 1) {
        dst[t] = src[t] + ((t >= off) ? src[t - off] : 0);
        __syncthreads();
        int* tq = src; src = dst; dst = tq;
    }
    if (t < B1B) ps[t] = src[t] - lnv;     // exclusive start
    __shared__ int cntS;
    if (t == 0) cntS = src[255];
    __syncthreads();
    int cnt = min(cntS, CAP);

    for (int i = t; i < cnt; i += 256) {
        int lo = 0, hi = B1B;
        while (hi - lo > 1) {
            int mid = (lo + hi) >> 1;
            if (ps[mid] <= i) lo = mid; else hi = mid;
        }
        int2 ed = tmp[lo * B1C + lb[lo] + (i - ps[lo])];
        stage[i] = ed;
        atomicAdd(&hist[ed.x & (BKN - 1)], 1);
        atomicAdd(&dsum[ed.x & (BKN - 1)], __int_as_float(ed.y));
    }
    __syncthreads();
    if (t < BKN) na[t] = hist[t];
    __syncthreads();
    int* s2 = na; int* d2 = nb;
#pragma unroll
    for (int off = 1; off < BKN; off <<= 1) {
        if (t < BKN) d2[t] = s2[t] + ((t >= off) ? s2[t - off] : 0);
        __syncthreads();
        int* tq = s2; s2 = d2; d2 = tq;
    }
    int node0 = b * BKN;
    if (t < BKN) {
        int lincl = s2[t];
        int lexcl = lincl - hist[t];
        lcur[t] = lexcl;
        int node = node0 + t;
        if (node < NN) {
            benode[node] = make_int2(b * CAP + lexcl, b * CAP + lincl);
            dinv[node]   = rsqrtf(1.0f + dsum[t]);   // 1.0 = self-loop weight
        }
    }
    __syncthreads();
    for (int i = t; i < cnt; i += 256) {
        int2 ed = stage[i];
        int pos = atomicAdd(&lcur[ed.x & (BKN - 1)], 1);
        __half hw = __float2half(__int_as_float(ed.y));
        u32 hb = (u32)__half_as_ushort(hw);
        sortedU[pos] = (hb << 16) | (u32)(ed.x >> BKS);   // {f16 w | src}
    }
    __syncthreads();
    for (int i = t; i < cnt; i += 256) sedge[b * CAP + i] = sortedU[i];
}

// ---------------- dense: Y[n,64] = X[n,64] @ W[64,64], all fp32 ----------------

__global__ __launch_bounds__(256) void k_mm64(const float* __restrict__ X,
                                              const float* __restrict__ W,
                                              float* __restrict__ Y) {
    __shared__ float sW[64 * 64];
    __shared__ float sX[16][64];
    int tid = threadIdx.x;
    int c  = tid & 63;
    int wv = tid >> 6;
    for (int i = tid; i < 64 * 64; i += 256) sW[i] = W[i];
    int r0 = blockIdx.x * 16;
#pragma unroll
    for (int i = tid; i < 16 * 64; i += 256)
        sX[i >> 6][i & 63] = X[(size_t)(r0 + (i >> 6)) * 64 + (i & 63)];
    __syncthreads();
    int rb = wv * 4;
    float a0 = 0.f, a1 = 0.f, a2 = 0.f, a3 = 0.f;
#pragma unroll
    for (int k = 0; k < 64; k += 4) {
        float4 x0 = *(const float4*)&sX[rb + 0][k];
        float4 x1 = *(const float4*)&sX[rb + 1][k];
        float4 x2 = *(const float4*)&sX[rb + 2][k];
        float4 x3 = *(const float4*)&sX[rb + 3][k];
        float wA = sW[(k + 0) * 64 + c];
        float wB = sW[(k + 1) * 64 + c];
        float wC = sW[(k + 2) * 64 + c];
        float wD = sW[(k + 3) * 64 + c];
        a0 += x0.x * wA + x0.y * wB + x0.z * wC + x0.w * wD;
        a1 += x1.x * wA + x1.y * wB + x1.z * wC + x1.w * wD;
        a2 += x2.x * wA + x2.y * wB + x2.z * wC + x2.w * wD;
        a3 += x3.x * wA + x3.y * wB + x3.z * wC + x3.w * wD;
    }
    Y[(size_t)(r0 + rb + 0) * 64 + c] = a0;
    Y[(size_t)(r0 + rb + 1) * 64 + c] = a1;
    Y[(size_t)(r0 + rb + 2) * 64 + c] = a2;
    Y[(size_t)(r0 + rb + 3) * 64 + c] = a3;
}

// ---------------- aggregation: TWO nodes per wave, fp32 features (no unpack) ----
// 32-lane half per node: 4 edge slots x 8 fg-lanes. Each lane loads features
// fg*4..fg*4+3 and fg*4+32..+35 as two float4 (coalesced 128B row halves).
// Inner step: 2 loads + 8 fma + 2 shfl (vs 19 instr with bf16 unpack).

template<bool HEAD>
__global__ __launch_bounds__(256) void k_agg(const float* __restrict__ A,
                                             const int2* __restrict__ benode,
                                             const u32* __restrict__ sedge,
                                             const float* __restrict__ dinv,
                                             const float* __restrict__ bias,
                                             float* __restrict__ B,
                                             const float* __restrict__ Wout,
                                             const float* __restrict__ bout,
                                             float* __restrict__ out) {
    __shared__ float sWout[64 * NCLS];
    __shared__ float sh[8][64];
    int tid  = threadIdx.x;
    int wv   = tid >> 6;
    int lane = tid & 63;
    int half = lane >> 5;                 // node within the wave
    int sub  = lane & 31;
    int slot = sub >> 3;                  // 0..3 edge slot
    int fg   = sub & 7;                   // feature group
    int node = blockIdx.x * 8 + wv * 2 + half;   // 6250*8 = 50000 exact
    if (HEAD) {
        for (int i = tid; i < 64 * NCLS; i += 256) sWout[i] = Wout[i];
    }
    int2 be = benode[node];
    int beg = be.x;
    int deg = be.y - be.x;
    float acc[8] = {0.f, 0.f, 0.f, 0.f, 0.f, 0.f, 0.f, 0.f};

    // ---- batch 0: edges 0..min(deg,32)-1, fully unrolled (8 steps x 4 slots) ----
    {
        u32 e = (sub < deg) ? sedge[beg + sub] : 0u;              // w=0 pad
        int s_own = (int)(e & 0xffffu);
        float wf = __half2float(__ushort_as_half((u16)(e >> 16)));
        float nmr = wf * dinv[s_own];                             // w * dinv[src]
        int mval = min(32, deg);
#pragma unroll
        for (int t = 0; t < 8; ++t) {
            if ((t << 2) < mval) {
                int idx = (half << 5) + (t << 2) + slot;
                int   s  = __shfl(s_own, idx);
                float nm = __shfl(nmr, idx);
                const float* ar = A + (size_t)s * 64 + (fg << 2);
                const float4 a0v = *(const float4*)ar;
                const float4 a1v = *(const float4*)(ar + 32);
                acc[0] += a0v.x * nm; acc[1] += a0v.y * nm;
                acc[2] += a0v.z * nm; acc[3] += a0v.w * nm;
                acc[4] += a1v.x * nm; acc[5] += a1v.y * nm;
                acc[6] += a1v.z * nm; acc[7] += a1v.w * nm;
            }
        }
    }
    // ---- remainder: deg > 32 (rare) ----
    for (int base = 32; base < deg; base += 32) {
        int i = base + sub;
        u32 e = (i < deg) ? sedge[beg + i] : 0u;
        int s_own = (int)(e & 0xffffu);
        float wf = __half2float(__ushort_as_half((u16)(e >> 16)));
        float nmr = wf * dinv[s_own];
        int m = min(32, deg - base);
        int steps = (m + 3) >> 2;
        for (int t = 0; t < steps; ++t) {
            int idx = (half << 5) + (t << 2) + slot;
            int   s  = __shfl(s_own, idx);
            float nm = __shfl(nmr, idx);
            const float* ar = A + (size_t)s * 64 + (fg << 2);
            const float4 a0v = *(const float4*)ar;
            const float4 a1v = *(const float4*)(ar + 32);
            acc[0] += a0v.x * nm; acc[1] += a0v.y * nm;
            acc[2] += a0v.z * nm; acc[3] += a0v.w * nm;
            acc[4] += a1v.x * nm; acc[5] += a1v.y * nm;
            acc[6] += a1v.z * nm; acc[7] += a1v.w * nm;
        }
    }
    // reduce across the 4 slots within each half
#pragma unroll
    for (int o = 8; o <= 16; o <<= 1) {
#pragma unroll
        for (int j = 0; j < 8; ++j) acc[j] += __shfl_xor(acc[j], o);
    }
    if (slot == 0) {                       // 8 lanes per half
        float d = dinv[node];
        float d2 = d * d;
        const float* ar = A + (size_t)node * 64 + (fg << 2);
        const float4 s0 = *(const float4*)ar;
        const float4 s1 = *(const float4*)(ar + 32);
        const float4 b0 = *(const float4*)(bias + (fg << 2));
        const float4 b1 = *(const float4*)(bias + (fg << 2) + 32);
        float4 v0, v1;
        v0.x = fmaxf(acc[0] * d + s0.x * d2 + b0.x, 0.f);
        v0.y = fmaxf(acc[1] * d + s0.y * d2 + b0.y, 0.f);
        v0.z = fmaxf(acc[2] * d + s0.z * d2 + b0.z, 0.f);
        v0.w = fmaxf(acc[3] * d + s0.w * d2 + b0.w, 0.f);
        v1.x = fmaxf(acc[4] * d + s1.x * d2 + b1.x, 0.f);
        v1.y = fmaxf(acc[5] * d + s1.y * d2 + b1.y, 0.f);
        v1.z = fmaxf(acc[6] * d + s1.z * d2 + b1.z, 0.f);
        v1.w = fmaxf(acc[7] * d + s1.w * d2 + b1.w, 0.f);
        float* br = B + (size_t)node * 64 + (fg << 2);
        *(float4*)br = v0;
        *(float4*)(br + 32) = v1;
        if (HEAD) {
            int r = wv * 2 + half;
            *(float4*)&sh[r][(fg << 2)] = v0;
            *(float4*)&sh[r][(fg << 2) + 32] = v1;
        }
    }
    if (HEAD) {
        __syncthreads();
        int nib  = tid >> 5;               // node-in-block 0..7
        int sub2 = tid & 31;
        int c = sub2 & 15, q = sub2 >> 4;
        const float* hrow = sh[nib];
        float p = 0.f;
#pragma unroll
        for (int k = 0; k < 32; ++k)
            p += hrow[q * 32 + k] * sWout[(q * 32 + k) * NCLS + c];
        p += __shfl_xor(p, 16);
        p += bout[c];
        float mx = p;
#pragma unroll
        for (int o = 8; o >= 1; o >>= 1) mx = fmaxf(mx, __shfl_xor(mx, o, 16));
        float ex = expf(p - mx);
        float s = ex;
#pragma unroll
        for (int o = 8; o >= 1; o >>= 1) s += __shfl_xor(s, o, 16);
        if (q == 0) out[(size_t)(blockIdx.x * 8 + nib) * NCLS + c] = ex / s;
    }
}

// ---------------- launch ----------------

extern "C" void kernel_launch(void* const* d_in, const int* in_sizes, int n_in,
                              void* d_out, int out_size, void* d_ws, size_t ws_size,
                              hipStream_t stream) {
    const float* x    = (const float*)d_in[0];
    const int*   ei   = (const int*)d_in[1];
    const float* ew   = (const float*)d_in[2];
    const float* W1   = (const float*)d_in[3];
    const float* b1   = (const float*)d_in[4];
    const float* W2   = (const float*)d_in[5];
    const float* b2   = (const float*)d_in[6];
    const float* Wout = (const float*)d_in[7];
    const float* bout = (const float*)d_in[8];
    const int* row = ei;
    const int* col = ei + NE;

    // workspace (all dense regions; ~38 MB)
    int*   ip     = (int*)d_ws;
    int2*  benode = (int2*)ip;                        // 50048 int2 -> 100096 ints
    float* dinv   = (float*)(ip + 100096);            // 50048
    int*   ghL    = ip + 150144;                      // 196*512 = 100352
    int*   ghH    = ghL + 100352;                     // 100352
    u32*   sedge  = (u32*)(ip + 350848);              // NBK*CAP u32 (4 MB)
    int2*  tmp    = (int2*)(ip + 350848 + NBK * CAP); // B1B*B1C int2 (6.4 MB)
    float* A      = (float*)(tmp + (size_t)B1B * B1C);// NN*64 f32 (12.8 MB)
    float* B      = A + (size_t)NN * F;               // NN*64 f32 (12.8 MB)

    // layer-1 matmul (independent of the sort)
    k_mm64<<<NN / 16, 256, 0, stream>>>(x, W1, A);

    // sort pipeline: dense local sort -> per-bucket merge
    k_local<<<B1B, 512, 0, stream>>>(row, col, ew, tmp, ghL, ghH);
    k_bucket2<<<NBK, 256, 0, stream>>>(tmp, ghL, ghH, sedge, benode, dinv);

    // layer 1 aggregation
    k_agg<false><<<NN / 8, 256, 0, stream>>>(A, benode, sedge, dinv, b1, B,
                                             nullptr, nullptr, nullptr);
    // layer 2 + fused head
    k_mm64<<<NN / 16, 256, 0, stream>>>(B, W2, A);
    k_agg<true><<<NN / 8, 256, 0, stream>>>(A, benode, sedge, dinv, b2, B,
                                            Wout, bout, (float*)d_out);
}

// Round 15
// 183.091 us; speedup vs baseline: 1.1294x; 1.1294x over previous
//
#include <hip/hip_runtime.h>
#include <hip/hip_fp16.h>
#include <math.h>

#define NN 50000
#define NE 800000
#define F 64
#define NCLS 16

#define BKS 7              // log2(nodes per bucket)
#define BKN 128            // nodes per bucket
#define NBK 391            // ceil(50000/128)
#define CAP 2560           // sedge slots per bucket region (avg 2048, +11 sigma)
#define B1C 4096           // edges per k_local block (dense chunk)
#define B1B 196            // ceil(NE/B1C)

typedef unsigned short u16;
typedef unsigned int u32;
typedef __attribute__((ext_vector_type(8))) unsigned short ushort8v;

__device__ __forceinline__ float bf2f(u16 h) {
    return __uint_as_float((unsigned)h << 16);
}
__device__ __forceinline__ u16 f2bf(float f) {   // round-nearest-even
    unsigned u = __float_as_uint(f);
    return (u16)((u + 0x7fffu + ((u >> 16) & 1u)) >> 16);
}

// ---------------- pass 1: per-block LDS sort by bucket, DENSE writeback ----------

__global__ __launch_bounds__(512) void k_local(const int* __restrict__ row,
                                               const int* __restrict__ col,
                                               const float* __restrict__ w,
                                               int2* __restrict__ tmp,
                                               int* __restrict__ ghL,
                                               int* __restrict__ ghH) {
    __shared__ int hist[512], sa[512], sb[512], lcur[512];
    __shared__ int2 stage[B1C];
    int t = threadIdx.x;
    int e0 = blockIdx.x * B1C;
    int cnt = min(B1C, NE - e0);
    hist[t] = 0;
    __syncthreads();

    int mykey[8]; int myb[8]; int myw[8]; bool myv[8];
#pragma unroll
    for (int k = 0; k < 8; ++k) {
        int i = t + k * 512;
        myv[k] = (i < cnt);
        if (myv[k]) {
            int e = e0 + i;
            int c = col[e];
            myb[k]   = c >> BKS;
            mykey[k] = (row[e] << BKS) | (c & (BKN - 1));
            myw[k]   = __float_as_int(w[e]);
            atomicAdd(&hist[myb[k]], 1);
        }
    }
    __syncthreads();

    sa[t] = hist[t];
    __syncthreads();
    int* src = sa; int* dst = sb;
#pragma unroll
    for (int off = 1; off < 512; off <<= 1) {
        dst[t] = src[t] + ((t >= off) ? src[t - off] : 0);
        __syncthreads();
        int* tq = src; src = dst; dst = tq;
    }
    int lex = src[t] - hist[t];
    lcur[t] = lex;
    ghL[blockIdx.x * 512 + t] = lex;       // run start within this block's chunk
    ghH[blockIdx.x * 512 + t] = hist[t];   // run length
    __syncthreads();

#pragma unroll
    for (int k = 0; k < 8; ++k) {
        if (myv[k]) {
            int pos = atomicAdd(&lcur[myb[k]], 1);
            stage[pos] = make_int2(mykey[k], myw[k]);
        }
    }
    __syncthreads();

    for (int i = t; i < cnt; i += 512) tmp[e0 + i] = stage[i];
}

// ---------------- pass 2: one block per bucket: gather runs, node sort, dense out --
// Final sedge record = 4 bytes: (f16(w) << 16) | src.  dinv from exact f32 dsum.

__global__ __launch_bounds__(256) void k_bucket2(const int2* __restrict__ tmp,
                                                 const int* __restrict__ ghL,
                                                 const int* __restrict__ ghH,
                                                 u32* __restrict__ sedge,
                                                 int2* __restrict__ benode,
                                                 float* __restrict__ dinv) {
    __shared__ int2 stage[CAP];      // 20 KB
    __shared__ u32 sortedU[CAP];     // 10 KB
    __shared__ int lb[200], ps[200];
    __shared__ int ssa[256], ssb[256];
    __shared__ int hist[BKN], na[BKN], nb[BKN], lcur[BKN];
    __shared__ float dsum[BKN];
    int b = blockIdx.x;
    int t = threadIdx.x;
    int lnv = 0;
    if (t < B1B) {
        lb[t] = ghL[t * 512 + b];
        lnv   = ghH[t * 512 + b];
    }
    if (t < BKN) { hist[t] = 0; dsum[t] = 0.f; }
    ssa[t] = lnv;
    __syncthreads();
    int* src = ssa; int* dst = ssb;
#pragma unroll
    for (int off = 1; off < 256; off <<= 1) {
        dst[t] = src[t] + ((t >= off) ? src[t - off] : 0);
        __syncthreads();
        int* tq = src; src = dst; dst = tq;
    }
    if (t < B1B) ps[t] = src[t] - lnv;     // exclusive start
    __shared__ int cntS;
    if (t == 0) cntS = src[255];
    __syncthreads();
    int cnt = min(cntS, CAP);

    for (int i = t; i < cnt; i += 256) {
        int lo = 0, hi = B1B;
        while (hi - lo > 1) {
            int mid = (lo + hi) >> 1;
            if (ps[mid] <= i) lo = mid; else hi = mid;
        }
        int2 ed = tmp[lo * B1C + lb[lo] + (i - ps[lo])];
        stage[i] = ed;
        atomicAdd(&hist[ed.x & (BKN - 1)], 1);
        atomicAdd(&dsum[ed.x & (BKN - 1)], __int_as_float(ed.y));
    }
    __syncthreads();
    if (t < BKN) na[t] = hist[t];
    __syncthreads();
    int* s2 = na; int* d2 = nb;
#pragma unroll
    for (int off = 1; off < BKN; off <<= 1) {
        if (t < BKN) d2[t] = s2[t] + ((t >= off) ? s2[t - off] : 0);
        __syncthreads();
        int* tq = s2; s2 = d2; d2 = tq;
    }
    int node0 = b * BKN;
    if (t < BKN) {
        int lincl = s2[t];
        int lexcl = lincl - hist[t];
        lcur[t] = lexcl;
        int node = node0 + t;
        if (node < NN) {
            benode[node] = make_int2(b * CAP + lexcl, b * CAP + lincl);
            dinv[node]   = rsqrtf(1.0f + dsum[t]);   // 1.0 = self-loop weight
        }
    }
    __syncthreads();
    for (int i = t; i < cnt; i += 256) {
        int2 ed = stage[i];
        int pos = atomicAdd(&lcur[ed.x & (BKN - 1)], 1);
        __half hw = __float2half(__int_as_float(ed.y));
        u32 hb = (u32)__half_as_ushort(hw);
        sortedU[pos] = (hb << 16) | (u32)(ed.x >> BKS);   // {f16 w | src}
    }
    __syncthreads();
    for (int i = t; i < cnt; i += 256) sedge[b * CAP + i] = sortedU[i];
}

// ---------------- dense: A[n,64] = x[n,64] @ W1 -> bf16 (layer 1 only) ----------

__global__ __launch_bounds__(256) void k_mm64(const float* __restrict__ X,
                                              const float* __restrict__ W,
                                              u16* __restrict__ Y) {
    __shared__ float sW[64 * 64];
    __shared__ float sX[16][64];
    int tid = threadIdx.x;
    int c  = tid & 63;
    int wv = tid >> 6;
    for (int i = tid; i < 64 * 64; i += 256) sW[i] = W[i];
    int r0 = blockIdx.x * 16;
#pragma unroll
    for (int i = tid; i < 16 * 64; i += 256)
        sX[i >> 6][i & 63] = X[(size_t)(r0 + (i >> 6)) * 64 + (i & 63)];
    __syncthreads();
    int rb = wv * 4;
    float a0 = 0.f, a1 = 0.f, a2 = 0.f, a3 = 0.f;
#pragma unroll
    for (int k = 0; k < 64; k += 4) {
        float4 x0 = *(const float4*)&sX[rb + 0][k];
        float4 x1 = *(const float4*)&sX[rb + 1][k];
        float4 x2 = *(const float4*)&sX[rb + 2][k];
        float4 x3 = *(const float4*)&sX[rb + 3][k];
        float wA = sW[(k + 0) * 64 + c];
        float wB = sW[(k + 1) * 64 + c];
        float wC = sW[(k + 2) * 64 + c];
        float wD = sW[(k + 3) * 64 + c];
        a0 += x0.x * wA + x0.y * wB + x0.z * wC + x0.w * wD;
        a1 += x1.x * wA + x1.y * wB + x1.z * wC + x1.w * wD;
        a2 += x2.x * wA + x2.y * wB + x2.z * wC + x2.w * wD;
        a3 += x3.x * wA + x3.y * wB + x3.z * wC + x3.w * wD;
    }
    Y[(size_t)(r0 + rb + 0) * 64 + c] = f2bf(a0);
    Y[(size_t)(r0 + rb + 1) * 64 + c] = f2bf(a1);
    Y[(size_t)(r0 + rb + 2) * 64 + c] = f2bf(a2);
    Y[(size_t)(r0 + rb + 3) * 64 + c] = f2bf(a3);
}

// ---------------- fused layer-1 agg + ReLU + (h1 @ W2) -> bf16 A2 ----------------
// Aggregation identical to R13's 2-node/wave bf16 kernel; h1 never touches global.
// Epilogue: 8 node-rows in LDS, 256 threads compute h2 = relu(h1) @ W2 (W2 in LDS).

__global__ __launch_bounds__(256) void k_aggmm(const u16* __restrict__ A,
                                               const int2* __restrict__ benode,
                                               const u32* __restrict__ sedge,
                                               const float* __restrict__ dinv,
                                               const float* __restrict__ bias,
                                               const float* __restrict__ W2,
                                               u16* __restrict__ A2) {
    __shared__ float sW2[64 * 64];   // 16 KB
    __shared__ float sh[8][64];      // 2 KB
    int tid  = threadIdx.x;
    int wv   = tid >> 6;
    int lane = tid & 63;
    int half = lane >> 5;
    int sub  = lane & 31;
    int slot = sub >> 3;
    int fg   = sub & 7;
    int node = blockIdx.x * 8 + wv * 2 + half;   // 6250*8 = 50000 exact
    for (int i = tid; i < 64 * 64; i += 256) sW2[i] = W2[i];

    int2 be = benode[node];
    int beg = be.x;
    int deg = be.y - be.x;
    float acc[8] = {0.f, 0.f, 0.f, 0.f, 0.f, 0.f, 0.f, 0.f};

    {
        u32 e = (sub < deg) ? sedge[beg + sub] : 0u;
        int s_own = (int)(e & 0xffffu);
        float wf = __half2float(__ushort_as_half((u16)(e >> 16)));
        float nmr = wf * dinv[s_own];
        int mval = min(32, deg);
#pragma unroll
        for (int t = 0; t < 8; ++t) {
            if ((t << 2) < mval) {
                int idx = (half << 5) + (t << 2) + slot;
                int   s  = __shfl(s_own, idx);
                float nm = __shfl(nmr, idx);
                const ushort8v a = *(const ushort8v*)(A + (size_t)s * 64 + (fg << 3));
#pragma unroll
                for (int j = 0; j < 8; ++j) acc[j] += bf2f(a[j]) * nm;
            }
        }
    }
    for (int base = 32; base < deg; base += 32) {
        int i = base + sub;
        u32 e = (i < deg) ? sedge[beg + i] : 0u;
        int s_own = (int)(e & 0xffffu);
        float wf = __half2float(__ushort_as_half((u16)(e >> 16)));
        float nmr = wf * dinv[s_own];
        int m = min(32, deg - base);
        int steps = (m + 3) >> 2;
        for (int t = 0; t < steps; ++t) {
            int idx = (half << 5) + (t << 2) + slot;
            int   s  = __shfl(s_own, idx);
            float nm = __shfl(nmr, idx);
            const ushort8v a = *(const ushort8v*)(A + (size_t)s * 64 + (fg << 3));
#pragma unroll
            for (int j = 0; j < 8; ++j) acc[j] += bf2f(a[j]) * nm;
        }
    }
#pragma unroll
    for (int o = 8; o <= 16; o <<= 1) {
#pragma unroll
        for (int j = 0; j < 8; ++j) acc[j] += __shfl_xor(acc[j], o);
    }
    if (slot == 0) {
        float d = dinv[node];
        float d2 = d * d;
        const ushort8v self = *(const ushort8v*)(A + (size_t)node * 64 + (fg << 3));
        const float4 bb0 = *(const float4*)(bias + (fg << 3));
        const float4 bb1 = *(const float4*)(bias + (fg << 3) + 4);
        float bbv[8] = {bb0.x, bb0.y, bb0.z, bb0.w, bb1.x, bb1.y, bb1.z, bb1.w};
        int r = wv * 2 + half;
#pragma unroll
        for (int j = 0; j < 8; ++j)
            sh[r][(fg << 3) + j] = fmaxf(acc[j] * d + bf2f(self[j]) * d2 + bbv[j], 0.f);
    }
    __syncthreads();

    // ---- fused mm: h2[nib][c], c and c+32, from LDS ----
    int nib = tid >> 5;            // 0..7 (matches wv*2+half ordering)
    int c   = tid & 31;
    const float* hrow = sh[nib];
    float p0 = 0.f, p1 = 0.f;
#pragma unroll
    for (int k = 0; k < 64; k += 4) {
        float4 hv = *(const float4*)&hrow[k];
        p0 += hv.x * sW2[(k + 0) * 64 + c] + hv.y * sW2[(k + 1) * 64 + c]
            + hv.z * sW2[(k + 2) * 64 + c] + hv.w * sW2[(k + 3) * 64 + c];
        p1 += hv.x * sW2[(k + 0) * 64 + c + 32] + hv.y * sW2[(k + 1) * 64 + c + 32]
            + hv.z * sW2[(k + 2) * 64 + c + 32] + hv.w * sW2[(k + 3) * 64 + c + 32];
    }
    int onode = blockIdx.x * 8 + nib;
    A2[(size_t)onode * 64 + c]      = f2bf(p0);
    A2[(size_t)onode * 64 + c + 32] = f2bf(p1);
}

// ---------------- layer-2 aggregation + fused head (unchanged from R13) ----------

__global__ __launch_bounds__(256) void k_agg2(const u16* __restrict__ A,
                                              const int2* __restrict__ benode,
                                              const u32* __restrict__ sedge,
                                              const float* __restrict__ dinv,
                                              const float* __restrict__ bias,
                                              const float* __restrict__ Wout,
                                              const float* __restrict__ bout,
                                              float* __restrict__ out) {
    __shared__ float sWout[64 * NCLS];
    __shared__ float sh[8][64];
    int tid  = threadIdx.x;
    int wv   = tid >> 6;
    int lane = tid & 63;
    int half = lane >> 5;
    int sub  = lane & 31;
    int slot = sub >> 3;
    int fg   = sub & 7;
    int node = blockIdx.x * 8 + wv * 2 + half;
    for (int i = tid; i < 64 * NCLS; i += 256) sWout[i] = Wout[i];
    int2 be = benode[node];
    int beg = be.x;
    int deg = be.y - be.x;
    float acc[8] = {0.f, 0.f, 0.f, 0.f, 0.f, 0.f, 0.f, 0.f};
    {
        u32 e = (sub < deg) ? sedge[beg + sub] : 0u;
        int s_own = (int)(e & 0xffffu);
        float wf = __half2float(__ushort_as_half((u16)(e >> 16)));
        float nmr = wf * dinv[s_own];
        int mval = min(32, deg);
#pragma unroll
        for (int t = 0; t < 8; ++t) {
            if ((t << 2) < mval) {
                int idx = (half << 5) + (t << 2) + slot;
                int   s  = __shfl(s_own, idx);
                float nm = __shfl(nmr, idx);
                const ushort8v a = *(const ushort8v*)(A + (size_t)s * 64 + (fg << 3));
#pragma unroll
                for (int j = 0; j < 8; ++j) acc[j] += bf2f(a[j]) * nm;
            }
        }
    }
    for (int base = 32; base < deg; base += 32) {
        int i = base + sub;
        u32 e = (i < deg) ? sedge[beg + i] : 0u;
        int s_own = (int)(e & 0xffffu);
        float wf = __half2float(__ushort_as_half((u16)(e >> 16)));
        float nmr = wf * dinv[s_own];
        int m = min(32, deg - base);
        int steps = (m + 3) >> 2;
        for (int t = 0; t < steps; ++t) {
            int idx = (half << 5) + (t << 2) + slot;
            int   s  = __shfl(s_own, idx);
            float nm = __shfl(nmr, idx);
            const ushort8v a = *(const ushort8v*)(A + (size_t)s * 64 + (fg << 3));
#pragma unroll
            for (int j = 0; j < 8; ++j) acc[j] += bf2f(a[j]) * nm;
        }
    }
#pragma unroll
    for (int o = 8; o <= 16; o <<= 1) {
#pragma unroll
        for (int j = 0; j < 8; ++j) acc[j] += __shfl_xor(acc[j], o);
    }
    if (slot == 0) {
        float d = dinv[node];
        float d2 = d * d;
        const ushort8v self = *(const ushort8v*)(A + (size_t)node * 64 + (fg << 3));
        const float4 bb0 = *(const float4*)(bias + (fg << 3));
        const float4 bb1 = *(const float4*)(bias + (fg << 3) + 4);
        float bbv[8] = {bb0.x, bb0.y, bb0.z, bb0.w, bb1.x, bb1.y, bb1.z, bb1.w};
        int r = wv * 2 + half;
#pragma unroll
        for (int j = 0; j < 8; ++j)
            sh[r][(fg << 3) + j] = fmaxf(acc[j] * d + bf2f(self[j]) * d2 + bbv[j], 0.f);
    }
    __syncthreads();
    int nib  = tid >> 5;
    int sub2 = tid & 31;
    int c = sub2 & 15, q = sub2 >> 4;
    const float* hrow = sh[nib];
    float p = 0.f;
#pragma unroll
    for (int k = 0; k < 32; ++k)
        p += hrow[q * 32 + k] * sWout[(q * 32 + k) * NCLS + c];
    p += __shfl_xor(p, 16);
    p += bout[c];
    float mx = p;
#pragma unroll
    for (int o = 8; o >= 1; o >>= 1) mx = fmaxf(mx, __shfl_xor(mx, o, 16));
    float ex = expf(p - mx);
    float s = ex;
#pragma unroll
    for (int o = 8; o >= 1; o >>= 1) s += __shfl_xor(s, o, 16);
    if (q == 0) out[(size_t)(blockIdx.x * 8 + nib) * NCLS + c] = ex / s;
}

// ---------------- launch ----------------

extern "C" void kernel_launch(void* const* d_in, const int* in_sizes, int n_in,
                              void* d_out, int out_size, void* d_ws, size_t ws_size,
                              hipStream_t stream) {
    const float* x    = (const float*)d_in[0];
    const int*   ei   = (const int*)d_in[1];
    const float* ew   = (const float*)d_in[2];
    const float* W1   = (const float*)d_in[3];
    const float* b1   = (const float*)d_in[4];
    const float* W2   = (const float*)d_in[5];
    const float* b2   = (const float*)d_in[6];
    const float* Wout = (const float*)d_in[7];
    const float* bout = (const float*)d_in[8];
    const int* row = ei;
    const int* col = ei + NE;

    // workspace
    int*   ip     = (int*)d_ws;
    int2*  benode = (int2*)ip;                        // 50048 int2
    float* dinv   = (float*)(ip + 100096);            // 50048
    int*   ghL    = ip + 150144;                      // 100352
    int*   ghH    = ghL + 100352;                     // 100352
    u32*   sedge  = (u32*)(ip + 350848);              // NBK*CAP u32 (4 MB)
    int2*  tmp    = (int2*)(ip + 350848 + NBK * CAP); // B1B*B1C int2 (6.4 MB)
    u16*   A      = (u16*)(tmp + (size_t)B1B * B1C);  // NN*64 bf16 (6.4 MB)
    u16*   B      = A + 3200000;                      // NN*64 bf16 (6.4 MB)

    // layer-1 matmul (independent of the sort)
    k_mm64<<<NN / 16, 256, 0, stream>>>(x, W1, A);

    // sort pipeline
    k_local<<<B1B, 512, 0, stream>>>(row, col, ew, tmp, ghL, ghH);
    k_bucket2<<<NBK, 256, 0, stream>>>(tmp, ghL, ghH, sedge, benode, dinv);

    // layer-1 agg + fused (relu @ W2) -> B holds A2
    k_aggmm<<<NN / 8, 256, 0, stream>>>(A, benode, sedge, dinv, b1, W2, B);

    // layer-2 agg + fused head
    k_agg2<<<NN / 8, 256, 0, stream>>>(B, benode, sedge, dinv, b2,
                                       Wout, bout, (float*)d_out);
}